// Round 2
// baseline (249.905 us; speedup 1.0000x reference)
//
#include <hip/hip_runtime.h>

// Problem constants (LinearCrossAttention)
#define BATCH 16
#define SEQ_N 4096
#define SEQ_M 1024
#define KDIM 512     // INPUT_DIM == COND_DIM == GEMM K
#define NHEADS 8
#define DHEAD 64
#define HIDDEN 512

typedef __attribute__((ext_vector_type(8))) short bf16x8;
typedef __attribute__((ext_vector_type(4))) float f32x4;
typedef unsigned short u16;
typedef unsigned int u32;

static __device__ __forceinline__ u16 f2bf(float f) {
  u32 u = __builtin_bit_cast(u32, f);
  u32 r = u + 0x7fffu + ((u >> 16) & 1u);   // round-to-nearest-even
  return (u16)(r >> 16);
}
static __device__ __forceinline__ bf16x8 ld_frag(const u16* p) {
  // 8B-aligned only (pad-4 rows), so 2x b64 then assemble
  uint2 lo = *(const uint2*)p;
  uint2 hi = *(const uint2*)(p + 4);
  uint4 u = make_uint4(lo.x, lo.y, hi.x, hi.y);
  return __builtin_bit_cast(bf16x8, u);
}

// ---------------------------------------------------------------------------
// Shared GEMM: C[b] = A[b] @ B[b] (+bias).  A: [O, 512] row-major (f32 or
// bf16).  B: [512, ldn] f32 row-major (transposed+converted into LDS).
// Out: [O, ldn] f32 or bf16.
// Grid: 1D, MT*NT*BATCH blocks, 256 threads.
// XCD co-scheduling: the MT m-tile blocks sharing one (ntile, batch) B-slice
// are mapped to dispatch ids congruent mod 8 -> same XCD -> B-slice fetched
// from HBM once, shared via that XCD's L2.  Requires NT*BATCH % 8 == 0.
// ---------------------------------------------------------------------------
template<bool A_BF16, bool OUT_BF16, bool BIAS, int MT, int NT>
__global__ __launch_bounds__(256, 4) void gemm_k512(
    const void* __restrict__ Ap, long a_bstride,
    const float* __restrict__ Bp, long b_bstride,
    void* __restrict__ Op, long o_bstride,
    const float* __restrict__ bias, int ldn)
{
  constexpr int LDT = 68;                     // 64 + 4 pad (136B row stride)
  __shared__ u16 Ash[128 * LDT];              // [row][k]
  __shared__ u16 Bsh[128 * LDT];              // [n][k]  (B transposed)

  // decode XCD-grouped block id: d = (g%8) + 8*((g/8)*MT + m), g = n + NT*b
  const int d = blockIdx.x;
  const int xcd = d & 7;
  const int s = d >> 3;
  const int mteil = s % MT;
  const int g = (s / MT) * 8 + xcd;
  const int b = g / NT;
  const long mtile = (long)mteil * 128;
  const long ntile = (long)(g % NT) * 128;

  const int t = threadIdx.x;
  const int lane = t & 63;
  const int wv = t >> 6;
  const int wr = (wv >> 1) * 64, wc = (wv & 1) * 64;
  const int lrow = lane & 15, lkh = lane >> 4;

  const float* Bb = Bp + (long)b * b_bstride;

  f32x4 acc[4][4] = {};

  for (int kt = 0; kt < KDIM; kt += 64) {
    // ---- stage A tile [128][64] ----
    if constexpr (A_BF16) {
      const u16* Ab = (const u16*)Ap + (long)b * a_bstride;
      #pragma unroll
      for (int i = 0; i < 4; ++i) {
        int idx = t + i * 256;
        int row = idx >> 3, kc = idx & 7;
        uint4 v = *(const uint4*)(Ab + (mtile + row) * KDIM + kt + kc * 8);
        u16* dst = &Ash[row * LDT + kc * 8];
        *(uint2*)dst       = make_uint2(v.x, v.y);
        *(uint2*)(dst + 4) = make_uint2(v.z, v.w);
      }
    } else {
      const float* Ab = (const float*)Ap + (long)b * a_bstride;
      #pragma unroll
      for (int i = 0; i < 4; ++i) {
        int idx = t + i * 256;
        int row = idx >> 3, kc = idx & 7;
        const float* src = Ab + (mtile + row) * KDIM + kt + kc * 8;
        float4 v0 = *(const float4*)src;
        float4 v1 = *(const float4*)(src + 4);
        u32 w0 = (u32)f2bf(v0.x) | ((u32)f2bf(v0.y) << 16);
        u32 w1 = (u32)f2bf(v0.z) | ((u32)f2bf(v0.w) << 16);
        u32 w2 = (u32)f2bf(v1.x) | ((u32)f2bf(v1.y) << 16);
        u32 w3 = (u32)f2bf(v1.z) | ((u32)f2bf(v1.w) << 16);
        u16* dst = &Ash[row * LDT + kc * 8];
        *(uint2*)dst       = make_uint2(w0, w1);
        *(uint2*)(dst + 4) = make_uint2(w2, w3);
      }
    }
    // ---- stage B tile transposed: Bsh[n][k] from B[k][n] (f32 -> bf16) ----
    #pragma unroll
    for (int i = 0; i < 2; ++i) {
      int idx = t + i * 256;
      int nq = idx & 31;
      int kq = ((idx >> 5) ^ ((idx >> 2) & 7)) & 15;  // bijective; spreads LDS write banks
      float rr[4][4];
      #pragma unroll
      for (int kk = 0; kk < 4; ++kk) {
        float4 v = *(const float4*)(Bb + (long)(kt + kq * 4 + kk) * ldn + ntile + nq * 4);
        rr[kk][0] = v.x; rr[kk][1] = v.y; rr[kk][2] = v.z; rr[kk][3] = v.w;
      }
      #pragma unroll
      for (int jj = 0; jj < 4; ++jj) {
        u32 w0 = (u32)f2bf(rr[0][jj]) | ((u32)f2bf(rr[1][jj]) << 16);
        u32 w1 = (u32)f2bf(rr[2][jj]) | ((u32)f2bf(rr[3][jj]) << 16);
        *(uint2*)&Bsh[(nq * 4 + jj) * LDT + kq * 4] = make_uint2(w0, w1);
      }
    }
    __syncthreads();
    // ---- MFMA: each wave owns a 64x64 quadrant, 4x4 frags of 16x16x32 ----
    #pragma unroll
    for (int kk = 0; kk < 2; ++kk) {
      bf16x8 af[4], bfr[4];
      #pragma unroll
      for (int mi = 0; mi < 4; ++mi)
        af[mi] = ld_frag(&Ash[(wr + mi * 16 + lrow) * LDT + kk * 32 + lkh * 8]);
      #pragma unroll
      for (int ni = 0; ni < 4; ++ni)
        bfr[ni] = ld_frag(&Bsh[(wc + ni * 16 + lrow) * LDT + kk * 32 + lkh * 8]);
      #pragma unroll
      for (int mi = 0; mi < 4; ++mi)
        #pragma unroll
        for (int ni = 0; ni < 4; ++ni)
          acc[mi][ni] = __builtin_amdgcn_mfma_f32_16x16x32_bf16(af[mi], bfr[ni], acc[mi][ni], 0, 0, 0);
    }
    __syncthreads();
  }
  // ---- epilogue: D row = (lane>>4)*4 + r, col = lane&15 ----
  #pragma unroll
  for (int mi = 0; mi < 4; ++mi) {
    #pragma unroll
    for (int r = 0; r < 4; ++r) {
      long gr = mtile + wr + mi * 16 + lkh * 4 + r;
      float bv = 0.0f;
      if constexpr (BIAS) bv = bias[gr];
      #pragma unroll
      for (int ni = 0; ni < 4; ++ni) {
        long gc = ntile + wc + ni * 16 + lrow;
        float v = acc[mi][ni][r] + bv;
        if constexpr (OUT_BF16)
          ((u16*)Op)[(long)b * o_bstride + gr * ldn + gc] = f2bf(v);
        else
          ((float*)Op)[(long)b * o_bstride + gr * ldn + gc] = v;
      }
    }
  }
}

// ---------------------------------------------------------------------------
// K2: per (b,h): softmax over m of K rows, ctx[d][e] = sum_m Kexp[d][m]*V[e][m]
// via MFMA (V's natural [e][m] layout IS the B-operand [col][k] layout).
// grid = B*H blocks, 256 threads (4 waves split the m/K dimension).
// ---------------------------------------------------------------------------
__global__ __launch_bounds__(256, 2) void softmax_context(
    const u16* __restrict__ kv, float* __restrict__ ctx)
{
  constexpr int LDE = 132;                    // 128 + 4 pad
  __shared__ float rowmax[64], rowinv[64];
  __shared__ u16 Ke[64 * LDE];
  __shared__ u16 Vs[64 * LDE];
  __shared__ float pr[64 * 68];

  const int bh = blockIdx.x;
  const u16* Kr = kv + (long)(bh >> 3) * (1024 * 1024) + (long)(bh & 7) * (64 * 1024);
  const u16* Vr = Kr + 512 * 1024;

  const int t = threadIdx.x;
  const int lane = t & 63, wv = t >> 6;
  const int lrow = lane & 15, lkh = lane >> 4;
  const int d4 = t >> 2, q4 = t & 3;

  // phase A: row max + 1/sum(exp)
  {
    const u16* row = Kr + d4 * 1024 + q4 * 256;
    float mx = -3e38f;
    for (int i = 0; i < 256; i += 8) {
      uint4 v = *(const uint4*)(row + i);
      u32 ws[4] = {v.x, v.y, v.z, v.w};
      #pragma unroll
      for (int j = 0; j < 4; ++j) {
        mx = fmaxf(mx, __builtin_bit_cast(float, ws[j] << 16));
        mx = fmaxf(mx, __builtin_bit_cast(float, ws[j] & 0xffff0000u));
      }
    }
    mx = fmaxf(mx, __shfl_xor(mx, 1));
    mx = fmaxf(mx, __shfl_xor(mx, 2));
    float s = 0.f;
    for (int i = 0; i < 256; i += 8) {
      uint4 v = *(const uint4*)(row + i);
      u32 ws[4] = {v.x, v.y, v.z, v.w};
      #pragma unroll
      for (int j = 0; j < 4; ++j) {
        s += __expf(__builtin_bit_cast(float, ws[j] << 16) - mx);
        s += __expf(__builtin_bit_cast(float, ws[j] & 0xffff0000u) - mx);
      }
    }
    s += __shfl_xor(s, 1);
    s += __shfl_xor(s, 2);
    if (q4 == 0) { rowmax[d4] = mx; rowinv[d4] = 1.f / s; }
  }
  __syncthreads();

  f32x4 cacc[4][4] = {};

  for (int mc = 0; mc < 8; ++mc) {
    // stage Ke (normalized exp, bf16) and Vs (copy) for 128-m chunk
    {
      int dd = t >> 2, j = t & 3;
      int m0 = mc * 128 + j * 32;
      float mx = rowmax[dd], inv = rowinv[dd];
      const u16* src = Kr + dd * 1024 + m0;
      u16* dst = &Ke[dd * LDE + j * 32];
      #pragma unroll
      for (int cq = 0; cq < 4; ++cq) {
        uint4 v = *(const uint4*)(src + cq * 8);
        u32 in[4] = {v.x, v.y, v.z, v.w};
        u32 out[4];
        #pragma unroll
        for (int j2 = 0; j2 < 4; ++j2) {
          float lo = __builtin_bit_cast(float, in[j2] << 16);
          float hi = __builtin_bit_cast(float, in[j2] & 0xffff0000u);
          out[j2] = (u32)f2bf(__expf(lo - mx) * inv) |
                    ((u32)f2bf(__expf(hi - mx) * inv) << 16);
        }
        *(uint2*)(dst + cq * 8)     = make_uint2(out[0], out[1]);
        *(uint2*)(dst + cq * 8 + 4) = make_uint2(out[2], out[3]);
      }
      const u16* vsrc = Vr + dd * 1024 + m0;
      u16* vdst = &Vs[dd * LDE + j * 32];
      #pragma unroll
      for (int cq = 0; cq < 4; ++cq) {
        uint4 v = *(const uint4*)(vsrc + cq * 8);
        *(uint2*)(vdst + cq * 8)     = make_uint2(v.x, v.y);
        *(uint2*)(vdst + cq * 8 + 4) = make_uint2(v.z, v.w);
      }
    }
    __syncthreads();
    // wave wv takes k-slice wv*32 of this 128-chunk
    bf16x8 ka[4], vb[4];
    #pragma unroll
    for (int mi = 0; mi < 4; ++mi)
      ka[mi] = ld_frag(&Ke[(mi * 16 + lrow) * LDE + wv * 32 + lkh * 8]);
    #pragma unroll
    for (int ni = 0; ni < 4; ++ni)
      vb[ni] = ld_frag(&Vs[(ni * 16 + lrow) * LDE + wv * 32 + lkh * 8]);
    #pragma unroll
    for (int mi = 0; mi < 4; ++mi)
      #pragma unroll
      for (int ni = 0; ni < 4; ++ni)
        cacc[mi][ni] = __builtin_amdgcn_mfma_f32_16x16x32_bf16(ka[mi], vb[ni], cacc[mi][ni], 0, 0, 0);
    __syncthreads();
  }

  // cross-wave reduce (serialized adds into pr)
  for (int w = 0; w < 4; ++w) {
    if (wv == w) {
      #pragma unroll
      for (int mi = 0; mi < 4; ++mi)
        #pragma unroll
        for (int ni = 0; ni < 4; ++ni)
          #pragma unroll
          for (int r = 0; r < 4; ++r) {
            float* p = &pr[(mi * 16 + lkh * 4 + r) * 68 + (ni * 16 + lrow)];
            float v = cacc[mi][ni][r];
            if (w == 0) *p = v; else *p += v;
          }
    }
    __syncthreads();
  }
  float* cg = ctx + (long)bh * 4096;
  for (int i = 0; i < 16; ++i) {
    int o = t + i * 256;
    cg[o] = 0.125f * pr[(o >> 6) * 68 + (o & 63)];  // fold q-scale (DIM_HEAD^-0.5)
  }
}

// ---------------------------------------------------------------------------
// K3a: U[b][o][h*64+d] = sum_e Wo[o][h*64+e] * ctx[b,h,d,e]   (scale folded)
// grid = (B*H, 4 d-quarters), 256 threads.
// ---------------------------------------------------------------------------
__global__ __launch_bounds__(256) void compose_u(
    const float* __restrict__ ctx, const float* __restrict__ Wo, u16* __restrict__ U)
{
  __shared__ float cs[16 * 64];
  const int bh = blockIdx.x, dq = blockIdx.y;
  const int b = bh >> 3, h = bh & 7;
  const int t = threadIdx.x;
  const float* cgrp = ctx + (long)bh * 4096 + dq * 16 * 64;
  for (int i = t; i < 1024; i += 256) cs[i] = cgrp[i];
  __syncthreads();
  #pragma unroll
  for (int rep = 0; rep < 2; ++rep) {
    int o = rep * 256 + t;
    const float* wrow = Wo + (long)o * HIDDEN + h * 64;
    float acc[16] = {};
    for (int e = 0; e < 64; ++e) {
      float w = wrow[e];
      #pragma unroll
      for (int dd = 0; dd < 16; ++dd) acc[dd] += w * cs[dd * 64 + e];
    }
    u16* urow = U + (long)b * (512 * 512) + (long)o * 512 + h * 64 + dq * 16;
    #pragma unroll
    for (int dd = 0; dd < 16; ++dd) urow[dd] = f2bf(acc[dd]);
  }
}

// ---------------------------------------------------------------------------
extern "C" void kernel_launch(void* const* d_in, const int* in_sizes, int n_in,
                              void* d_out, int out_size, void* d_ws, size_t ws_size,
                              hipStream_t stream)
{
  const float* x   = (const float*)d_in[0];  // [16, 512, 4096]
  const float* c   = (const float*)d_in[1];  // [16, 512, 1024]
  const float* Wq  = (const float*)d_in[2];  // [512, 512]
  const float* Wkv = (const float*)d_in[3];  // [1024, 512]
  const float* Wo  = (const float*)d_in[4];  // [512, 512]
  const float* bo  = (const float*)d_in[5];  // [512]

  // workspace layout (52.4 MB total)
  char* ws = (char*)d_ws;
  u16*   kv   = (u16*)ws;                      // 16*1024*1024 bf16 = 33.5 MB
  float* ctx  = (float*)(ws + 33554432);       // 16*8*64*64 f32    =  2.1 MB
  u16*   U    = (u16*)(ws + 35651584);         // 16*512*512 bf16   =  8.4 MB
  u16*   Weff = (u16*)(ws + 44040192);         // 16*512*512 bf16   =  8.4 MB

  // K1: kv[b] = Wkv @ c[b]            (A f32 shared, out bf16)  MT=8, NT=8
  gemm_k512<false, true, false, 8, 8><<<dim3(8 * 8 * 16), 256, 0, stream>>>(
      Wkv, 0, c, 512L * 1024, kv, 1024L * 1024, nullptr, 1024);
  // K2: softmax + context
  softmax_context<<<dim3(128), 256, 0, stream>>>(kv, ctx);
  // K3a: U = scale * Wo_h @ ctx_h^T
  compose_u<<<dim3(128, 4), 256, 0, stream>>>(ctx, Wo, U);
  // K3b: Weff[b] = U[b] @ Wq          (A bf16 per batch, B shared)  MT=4, NT=4
  gemm_k512<true, true, false, 4, 4><<<dim3(4 * 4 * 16), 256, 0, stream>>>(
      U, 512L * 512, Wq, 0, Weff, 512L * 512, nullptr, 512);
  // K4: Y[b] = Weff[b] @ x[b] + bo    (out f32 + bias)  MT=4, NT=32
  gemm_k512<true, false, true, 4, 32><<<dim3(4 * 32 * 16), 256, 0, stream>>>(
      Weff, 512L * 512, x, 512L * 4096, d_out, 512L * 4096, bo, 4096);
}

// Round 3
// 189.156 us; speedup vs baseline: 1.3212x; 1.3212x over previous
//
#include <hip/hip_runtime.h>

// LinearCrossAttention: B=16, N=4096, M=1024, C_in=C_cond=512, HIDDEN=512
#define KDIM 512

typedef __attribute__((ext_vector_type(8))) short bf16x8;
typedef __attribute__((ext_vector_type(4))) float f32x4;
typedef unsigned short u16;
typedef unsigned int u32;

static __device__ __forceinline__ u16 f2bf(float f) {
  u32 u = __builtin_bit_cast(u32, f);
  u32 r = u + 0x7fffu + ((u >> 16) & 1u);   // round-to-nearest-even
  return (u16)(r >> 16);
}
static __device__ __forceinline__ bf16x8 ld_frag(const u16* p) {
  uint2 lo = *(const uint2*)p;
  uint2 hi = *(const uint2*)(p + 4);
  uint4 u = make_uint4(lo.x, lo.y, hi.x, hi.y);
  return __builtin_bit_cast(bf16x8, u);
}

// ---------------------------------------------------------------------------
// prep: f32 -> bf16 (for Wkv), 8 elems/thread
// ---------------------------------------------------------------------------
__global__ __launch_bounds__(256) void cvt_f32_bf16(
    const float* __restrict__ src, u16* __restrict__ dst, int n8)
{
  int i = blockIdx.x * 256 + threadIdx.x;
  if (i >= n8) return;
  float4 a = *(const float4*)(src + (long)i * 8);
  float4 b = *(const float4*)(src + (long)i * 8 + 4);
  u32 w0 = (u32)f2bf(a.x) | ((u32)f2bf(a.y) << 16);
  u32 w1 = (u32)f2bf(a.z) | ((u32)f2bf(a.w) << 16);
  u32 w2 = (u32)f2bf(b.x) | ((u32)f2bf(b.y) << 16);
  u32 w3 = (u32)f2bf(b.z) | ((u32)f2bf(b.w) << 16);
  *(uint4*)(dst + (long)i * 8) = make_uint4(w0, w1, w2, w3);
}

// ---------------------------------------------------------------------------
// BM=512 GEMM: C[b][mtile*512 .. +512][ntile*128 .. +128] = A[b] @ B[b] (+bias)
// A: bf16 [*, 512] row-major.  B: f32 [512, ldn] row-major (transposed+cvt
// into LDS).  512 threads = 8 waves (4 M x 2 N), per-wave 128x64 output.
// Streaming operand (B) is read EXACTLY MT times total; A panel is small and
// L2-resident.  Register-prefetch double buffering: loads for step k+1 are
// issued before the MFMA phase of step k.
// CLUST (K4 only): 1-D grid, batch b pinned to XCD (b = bx&7 for first 8
// batches) so each XCD's L2 holds one batch's 512KB A-panel while its blocks
// stream DISTINCT x-slices (no MSHR stall-merging).
// ---------------------------------------------------------------------------
template<bool OUT_BF16, bool BIAS, bool CLUST>
__global__ __launch_bounds__(512, 2) void gemm_bm512(
    const u16* __restrict__ Ap, long a_bstride,
    const float* __restrict__ Bp, long b_bstride,
    void* __restrict__ Op, long o_bstride,
    const float* __restrict__ bias, int ldn)
{
  constexpr int LDT = 68;                 // 64 + 4 pad: 136B row stride, 0 bank conflicts measured
  __shared__ u16 Ash[512 * LDT];          // [row][k]   68 KB
  __shared__ u16 Bsh[128 * LDT];          // [n][k]     17 KB

  int mt, nt, b;
  if constexpr (CLUST) {                  // grid = 512 1-D (K4: MT=1, NT=32, B=16)
    const int bx = blockIdx.x;
    const int xcd = bx & 7, idx = bx >> 3;
    b = xcd + 8 * (idx >> 5);
    nt = idx & 31;
    mt = 0;
  } else {
    mt = blockIdx.x; nt = blockIdx.y; b = blockIdx.z;
  }
  const long mtile = (long)mt * 512;
  const long ntile = (long)nt * 128;
  const u16* Ab = Ap + (long)b * a_bstride + mtile * KDIM;
  const float* Bb = Bp + (long)b * b_bstride + ntile;

  const int t = threadIdx.x;
  const int lane = t & 63, wv = t >> 6;
  const int wm = wv >> 1, wn = wv & 1;    // 4 x 2 wave grid
  const int lrow = lane & 15, lkh = lane >> 4;

  // staging maps
  const int arow = t >> 3, akc = t & 7;             // A: rows arow+64i, 16B chunk akc
  const int nq = t & 31;                            // B: 4-col group
  const int kq = ((t >> 5) ^ ((t >> 2) & 7)) & 15;  // B: 4-row group (XOR-spread, bijective)

  f32x4 acc[8][4] = {};
  uint4 pa[8];
  float4 pb[4];

  // ---- prologue: load + write K-step 0 ----
  #pragma unroll
  for (int i = 0; i < 8; ++i)
    pa[i] = *(const uint4*)(Ab + (long)(arow + i * 64) * KDIM + akc * 8);
  #pragma unroll
  for (int kk = 0; kk < 4; ++kk)
    pb[kk] = *(const float4*)(Bb + (long)(kq * 4 + kk) * ldn + nq * 4);

  #pragma unroll
  for (int i = 0; i < 8; ++i) {
    u16* dst = &Ash[(arow + i * 64) * LDT + akc * 8];
    *(uint2*)dst       = make_uint2(pa[i].x, pa[i].y);
    *(uint2*)(dst + 4) = make_uint2(pa[i].z, pa[i].w);
  }
  {
    float r0[4] = {pb[0].x, pb[0].y, pb[0].z, pb[0].w};
    float r1[4] = {pb[1].x, pb[1].y, pb[1].z, pb[1].w};
    float r2[4] = {pb[2].x, pb[2].y, pb[2].z, pb[2].w};
    float r3[4] = {pb[3].x, pb[3].y, pb[3].z, pb[3].w};
    #pragma unroll
    for (int jj = 0; jj < 4; ++jj) {
      u32 w0 = (u32)f2bf(r0[jj]) | ((u32)f2bf(r1[jj]) << 16);
      u32 w1 = (u32)f2bf(r2[jj]) | ((u32)f2bf(r3[jj]) << 16);
      *(uint2*)&Bsh[(nq * 4 + jj) * LDT + kq * 4] = make_uint2(w0, w1);
    }
  }
  __syncthreads();

  for (int kt8 = 0; kt8 < 8; ++kt8) {
    const bool more = kt8 < 7;
    if (more) {                            // issue next-step loads BEFORE compute
      const int kt = (kt8 + 1) * 64;
      #pragma unroll
      for (int i = 0; i < 8; ++i)
        pa[i] = *(const uint4*)(Ab + (long)(arow + i * 64) * KDIM + kt + akc * 8);
      #pragma unroll
      for (int kk = 0; kk < 4; ++kk)
        pb[kk] = *(const float4*)(Bb + (long)(kt + kq * 4 + kk) * ldn + nq * 4);
    }
    // ---- MFMA from LDS ----
    #pragma unroll
    for (int kk = 0; kk < 2; ++kk) {
      bf16x8 bfr[4];
      #pragma unroll
      for (int ni = 0; ni < 4; ++ni)
        bfr[ni] = ld_frag(&Bsh[(wn * 64 + ni * 16 + lrow) * LDT + kk * 32 + lkh * 8]);
      #pragma unroll
      for (int mi = 0; mi < 8; ++mi) {
        bf16x8 af = ld_frag(&Ash[(wm * 128 + mi * 16 + lrow) * LDT + kk * 32 + lkh * 8]);
        #pragma unroll
        for (int ni = 0; ni < 4; ++ni)
          acc[mi][ni] = __builtin_amdgcn_mfma_f32_16x16x32_bf16(af, bfr[ni], acc[mi][ni], 0, 0, 0);
      }
    }
    __syncthreads();
    if (more) {                            // write prefetched regs -> LDS
      #pragma unroll
      for (int i = 0; i < 8; ++i) {
        u16* dst = &Ash[(arow + i * 64) * LDT + akc * 8];
        *(uint2*)dst       = make_uint2(pa[i].x, pa[i].y);
        *(uint2*)(dst + 4) = make_uint2(pa[i].z, pa[i].w);
      }
      float r0[4] = {pb[0].x, pb[0].y, pb[0].z, pb[0].w};
      float r1[4] = {pb[1].x, pb[1].y, pb[1].z, pb[1].w};
      float r2[4] = {pb[2].x, pb[2].y, pb[2].z, pb[2].w};
      float r3[4] = {pb[3].x, pb[3].y, pb[3].z, pb[3].w};
      #pragma unroll
      for (int jj = 0; jj < 4; ++jj) {
        u32 w0 = (u32)f2bf(r0[jj]) | ((u32)f2bf(r1[jj]) << 16);
        u32 w1 = (u32)f2bf(r2[jj]) | ((u32)f2bf(r3[jj]) << 16);
        *(uint2*)&Bsh[(nq * 4 + jj) * LDT + kq * 4] = make_uint2(w0, w1);
      }
      __syncthreads();
    }
  }

  // ---- epilogue: D row = (lane>>4)*4 + r, col = lane&15 ----
  #pragma unroll
  for (int mi = 0; mi < 8; ++mi) {
    #pragma unroll
    for (int r = 0; r < 4; ++r) {
      long gr = mtile + wm * 128 + mi * 16 + lkh * 4 + r;
      float bv = 0.0f;
      if constexpr (BIAS) bv = bias[gr];
      #pragma unroll
      for (int ni = 0; ni < 4; ++ni) {
        long gc = ntile + wn * 64 + ni * 16 + lrow;
        float v = acc[mi][ni][r] + bv;
        if constexpr (OUT_BF16)
          ((u16*)Op)[(long)b * o_bstride + gr * ldn + gc] = f2bf(v);
        else
          ((float*)Op)[(long)b * o_bstride + gr * ldn + gc] = v;
      }
    }
  }
}

// ---------------------------------------------------------------------------
// K2: per (b,h): softmax over m of K rows, ctx[d][e] = sum_m Kexp[d][m]*V[e][m]
// ---------------------------------------------------------------------------
__global__ __launch_bounds__(256, 2) void softmax_context(
    const u16* __restrict__ kv, float* __restrict__ ctx)
{
  constexpr int LDE = 132;
  __shared__ float rowmax[64], rowinv[64];
  __shared__ u16 Ke[64 * LDE];
  __shared__ u16 Vs[64 * LDE];
  __shared__ float pr[64 * 68];

  const int bh = blockIdx.x;
  const u16* Kr = kv + (long)(bh >> 3) * (1024 * 1024) + (long)(bh & 7) * (64 * 1024);
  const u16* Vr = Kr + 512 * 1024;

  const int t = threadIdx.x;
  const int lane = t & 63, wv = t >> 6;
  const int lrow = lane & 15, lkh = lane >> 4;
  const int d4 = t >> 2, q4 = t & 3;

  {
    const u16* row = Kr + d4 * 1024 + q4 * 256;
    float mx = -3e38f;
    for (int i = 0; i < 256; i += 8) {
      uint4 v = *(const uint4*)(row + i);
      u32 ws[4] = {v.x, v.y, v.z, v.w};
      #pragma unroll
      for (int j = 0; j < 4; ++j) {
        mx = fmaxf(mx, __builtin_bit_cast(float, ws[j] << 16));
        mx = fmaxf(mx, __builtin_bit_cast(float, ws[j] & 0xffff0000u));
      }
    }
    mx = fmaxf(mx, __shfl_xor(mx, 1));
    mx = fmaxf(mx, __shfl_xor(mx, 2));
    float s = 0.f;
    for (int i = 0; i < 256; i += 8) {
      uint4 v = *(const uint4*)(row + i);
      u32 ws[4] = {v.x, v.y, v.z, v.w};
      #pragma unroll
      for (int j = 0; j < 4; ++j) {
        s += __expf(__builtin_bit_cast(float, ws[j] << 16) - mx);
        s += __expf(__builtin_bit_cast(float, ws[j] & 0xffff0000u) - mx);
      }
    }
    s += __shfl_xor(s, 1);
    s += __shfl_xor(s, 2);
    if (q4 == 0) { rowmax[d4] = mx; rowinv[d4] = 1.f / s; }
  }
  __syncthreads();

  f32x4 cacc[4][4] = {};

  for (int mc = 0; mc < 8; ++mc) {
    {
      int dd = t >> 2, j = t & 3;
      int m0 = mc * 128 + j * 32;
      float mx = rowmax[dd], inv = rowinv[dd];
      const u16* src = Kr + dd * 1024 + m0;
      u16* dst = &Ke[dd * LDE + j * 32];
      #pragma unroll
      for (int cq = 0; cq < 4; ++cq) {
        uint4 v = *(const uint4*)(src + cq * 8);
        u32 in[4] = {v.x, v.y, v.z, v.w};
        u32 out[4];
        #pragma unroll
        for (int j2 = 0; j2 < 4; ++j2) {
          float lo = __builtin_bit_cast(float, in[j2] << 16);
          float hi = __builtin_bit_cast(float, in[j2] & 0xffff0000u);
          out[j2] = (u32)f2bf(__expf(lo - mx) * inv) |
                    ((u32)f2bf(__expf(hi - mx) * inv) << 16);
        }
        *(uint2*)(dst + cq * 8)     = make_uint2(out[0], out[1]);
        *(uint2*)(dst + cq * 8 + 4) = make_uint2(out[2], out[3]);
      }
      const u16* vsrc = Vr + dd * 1024 + m0;
      u16* vdst = &Vs[dd * LDE + j * 32];
      #pragma unroll
      for (int cq = 0; cq < 4; ++cq) {
        uint4 v = *(const uint4*)(vsrc + cq * 8);
        *(uint2*)(vdst + cq * 8)     = make_uint2(v.x, v.y);
        *(uint2*)(vdst + cq * 8 + 4) = make_uint2(v.z, v.w);
      }
    }
    __syncthreads();
    bf16x8 ka[4], vb[4];
    #pragma unroll
    for (int mi = 0; mi < 4; ++mi)
      ka[mi] = ld_frag(&Ke[(mi * 16 + lrow) * LDE + wv * 32 + lkh * 8]);
    #pragma unroll
    for (int ni = 0; ni < 4; ++ni)
      vb[ni] = ld_frag(&Vs[(ni * 16 + lrow) * LDE + wv * 32 + lkh * 8]);
    #pragma unroll
    for (int mi = 0; mi < 4; ++mi)
      #pragma unroll
      for (int ni = 0; ni < 4; ++ni)
        cacc[mi][ni] = __builtin_amdgcn_mfma_f32_16x16x32_bf16(ka[mi], vb[ni], cacc[mi][ni], 0, 0, 0);
    __syncthreads();
  }

  for (int w = 0; w < 4; ++w) {
    if (wv == w) {
      #pragma unroll
      for (int mi = 0; mi < 4; ++mi)
        #pragma unroll
        for (int ni = 0; ni < 4; ++ni)
          #pragma unroll
          for (int r = 0; r < 4; ++r) {
            float* p = &pr[(mi * 16 + lkh * 4 + r) * 68 + (ni * 16 + lrow)];
            float v = cacc[mi][ni][r];
            if (w == 0) *p = v; else *p += v;
          }
    }
    __syncthreads();
  }
  float* cg = ctx + (long)bh * 4096;
  for (int i = 0; i < 16; ++i) {
    int o = t + i * 256;
    cg[o] = 0.125f * pr[(o >> 6) * 68 + (o & 63)];  // fold q-scale
  }
}

// ---------------------------------------------------------------------------
// K3a: U[b][o][h*64+d] = sum_e Wo[o][h*64+e] * ctx[b,h,d,e]
// ---------------------------------------------------------------------------
__global__ __launch_bounds__(256) void compose_u(
    const float* __restrict__ ctx, const float* __restrict__ Wo, u16* __restrict__ U)
{
  __shared__ float cs[16 * 64];
  const int bh = blockIdx.x, dq = blockIdx.y;
  const int b = bh >> 3, h = bh & 7;
  const int t = threadIdx.x;
  const float* cgrp = ctx + (long)bh * 4096 + dq * 16 * 64;
  for (int i = t; i < 1024; i += 256) cs[i] = cgrp[i];
  __syncthreads();
  #pragma unroll
  for (int rep = 0; rep < 2; ++rep) {
    int o = rep * 256 + t;
    const float* wrow = Wo + (long)o * 512 + h * 64;
    float acc[16] = {};
    for (int e = 0; e < 64; ++e) {
      float w = wrow[e];
      #pragma unroll
      for (int dd = 0; dd < 16; ++dd) acc[dd] += w * cs[dd * 64 + e];
    }
    u16* urow = U + (long)b * (512 * 512) + (long)o * 512 + h * 64 + dq * 16;
    #pragma unroll
    for (int dd = 0; dd < 16; ++dd) urow[dd] = f2bf(acc[dd]);
  }
}

// ---------------------------------------------------------------------------
extern "C" void kernel_launch(void* const* d_in, const int* in_sizes, int n_in,
                              void* d_out, int out_size, void* d_ws, size_t ws_size,
                              hipStream_t stream)
{
  const float* x   = (const float*)d_in[0];  // [16, 512, 4096]
  const float* c   = (const float*)d_in[1];  // [16, 512, 1024]
  const float* Wq  = (const float*)d_in[2];  // [512, 512]
  const float* Wkv = (const float*)d_in[3];  // [1024, 512]
  const float* Wo  = (const float*)d_in[4];  // [512, 512]
  const float* bo  = (const float*)d_in[5];  // [512]

  // workspace layout (52.4 MB total, unchanged footprint)
  char* ws = (char*)d_ws;
  u16*   kv   = (u16*)ws;                      // 16*1024*1024 bf16 = 33.5 MB
  float* ctx  = (float*)(ws + 33554432);       // 16*8*64*64 f32    =  2.1 MB
  u16*   U    = (u16*)(ws + 35651584);         // 16*512*512 bf16   =  8.4 MB
  u16*   Weff = (u16*)(ws + 44040192);         // 16*512*512 bf16   =  8.4 MB
  u16*   Wkvb = (u16*)(ws + 44040192);         // 1 MB, overlaps Weff: consumed by K1
                                               // BEFORE K3b writes Weff (safe, deterministic)

  // K0: Wkv f32 -> bf16 (524288 elems / 8)
  cvt_f32_bf16<<<dim3(256), 256, 0, stream>>>(Wkv, Wkvb, 65536);
  // K1: kv[b] = Wkv @ c[b]   BM=512 (MT=2 on different XCDs), BN=128
  gemm_bm512<true, false, false><<<dim3(2, 8, 16), 512, 0, stream>>>(
      Wkvb, 0, c, 512L * 1024, kv, 1024L * 1024, nullptr, 1024);
  // K2: softmax + context
  softmax_context<<<dim3(128), 256, 0, stream>>>(kv, ctx);
  // K3a: U = scale * Wo_h @ ctx_h^T
  compose_u<<<dim3(128, 4), 256, 0, stream>>>(ctx, Wo, U);
  // K3b: Weff[b] = U[b] @ Wq
  gemm_bm512<true, false, false><<<dim3(1, 4, 16), 512, 0, stream>>>(
      U, 512L * 512, Wq, 0, Weff, 512L * 512, nullptr, 512);
  // K4: Y[b] = Weff[b] @ x[b] + bo   (batch-clustered XCD decode, 1-D grid)
  gemm_bm512<false, true, true><<<dim3(512), 512, 0, stream>>>(
      Weff, 512L * 512, x, 512L * 4096, d_out, 512L * 4096, bo, 4096);
}